// Round 7
// baseline (214.482 us; speedup 1.0000x reference)
//
#include <hip/hip_runtime.h>
#include <cstdint>
#include <cstddef>

// ---- types ----------------------------------------------------------------
typedef __bf16 bf8 __attribute__((ext_vector_type(8)));
typedef float f32x4 __attribute__((ext_vector_type(4)));
typedef float f32x2 __attribute__((ext_vector_type(2)));
typedef float f32x4u __attribute__((ext_vector_type(4), aligned(4)));
typedef float f32x3u __attribute__((ext_vector_type(3), aligned(4)));
typedef unsigned short us8 __attribute__((ext_vector_type(8)));
typedef unsigned short us4 __attribute__((ext_vector_type(4)));
typedef unsigned int u32x4 __attribute__((ext_vector_type(4)));
typedef unsigned int u32x2 __attribute__((ext_vector_type(2)));

__device__ __forceinline__ uint16_t f2b(float f) {
    uint32_t u = __builtin_bit_cast(uint32_t, f);
    u += 0x7FFFu + ((u >> 16) & 1u);          // RNE
    return (uint16_t)(u >> 16);
}
__device__ __forceinline__ float b2f(uint16_t h) {
    uint32_t u = ((uint32_t)h) << 16;
    return __builtin_bit_cast(float, u);
}
#if __has_builtin(__builtin_amdgcn_cvt_pk_bf16_f32)
__device__ __forceinline__ uint32_t pkbf(float a, float b) {
    auto r = __builtin_amdgcn_cvt_pk_bf16_f32(a, b);
    return __builtin_bit_cast(uint32_t, r);
}
#else
__device__ __forceinline__ uint32_t pkbf(float a, float b) {
    return (uint32_t)f2b(a) | ((uint32_t)f2b(b) << 16);
}
#endif
__device__ __forceinline__ f32x2 up01(uint32_t d) {
    f32x2 r;
    r[0] = __builtin_bit_cast(float, d << 16);
    r[1] = __builtin_bit_cast(float, d & 0xffff0000u);
    return r;
}
__device__ __forceinline__ float gelu_fast(float y) {
    float y3 = y * y * y;
    float z2 = 1.5957691216f * (y + 0.044715f * y3);
    float u = __expf(-z2);
    return y * __builtin_amdgcn_rcpf(1.0f + u);
}

#define MFMA(a, b, c) __builtin_amdgcn_mfma_f32_16x16x32_bf16( \
    __builtin_bit_cast(bf8, (a)), __builtin_bit_cast(bf8, (b)), (c), 0, 0, 0)

// ---- prep: cast+transpose weights into ws ---------------------------------
// ws layout (uint16_t): w1t[64][32] @0, w2t[64][64] @2048, w3t[3072][64] @6144
__global__ void prep_weights(const float* __restrict__ W1,
                             const float* __restrict__ W2,
                             const float* __restrict__ W3,
                             uint16_t* __restrict__ wt) {
    __shared__ float tile[32][33];
    int bx = blockIdx.x;
    if (bx < 192) {
        int kb = (bx & 1) * 32;
        int jb = (bx >> 1) * 32;
        int tx = threadIdx.x & 31, ty = threadIdx.x >> 5;   // 32 x 8
        #pragma unroll
        for (int l = 0; l < 4; ++l)
            tile[ty + 8 * l][tx] = W3[(size_t)(kb + ty + 8 * l) * 3072 + jb + tx];
        __syncthreads();
        #pragma unroll
        for (int l = 0; l < 4; ++l) {
            int j = jb + ty + 8 * l;
            wt[6144 + (size_t)j * 64 + kb + tx] = f2b(tile[tx][ty + 8 * l]);
        }
    } else {
        int t = (bx - 192) * 256 + threadIdx.x;   // 0..6143
        if (t < 2048) {                            // W1: [32][64]
            int i = t >> 6, j = t & 63;
            wt[j * 32 + i] = f2b(W1[t]);
        } else {                                   // W2: [64][64]
            int t2 = t - 2048;
            int k = t2 >> 6, j = t2 & 63;
            wt[2048 + j * 64 + k] = f2b(W2[t2]);
        }
    }
}

// ---- fused main kernel ----------------------------------------------------
// TLP round: grid = 1024 = 512 edge-groups x 2 o-halves. Each block: 256 thr
// (4 waves), phases B+C over 64 edges (duplicated across the half-pair; VALU
// is only ~31% busy so this is affordable and the 2nd read hits L3/L2), then
// phase D covers o in [half*16, half*16+16), 4 o per wave, 6 mt steps.
// -> 4096 waves = 12 waves/CU (LDS 46 KiB = 3 blocks/CU), vs 8 before.
// w3t L2 traffic unchanged (per-wave loads halve with the halved steps).
__global__ __launch_bounds__(256, 3) void pairconv_main(
    const float* __restrict__ edges, const float* __restrict__ feats,
    const float* __restrict__ basis,
    const float* __restrict__ b1, const float* __restrict__ g1, const float* __restrict__ be1,
    const float* __restrict__ b2, const float* __restrict__ g2, const float* __restrict__ be2,
    const uint16_t* __restrict__ wt, float* __restrict__ out) {

    __shared__ __align__(16) uint32_t sh_t01[64 * 100];   // 25.0 KiB (m0,m1 packed)
    __shared__ __align__(16) uint16_t sh_t2[64 * 104];    // 13.0 KiB (m2)
    __shared__ __align__(16) uint16_t sh_h[4][16 * 64];   // 8 KiB (h1 then h2)

    const int tid = threadIdx.x;
    const int e0 = (blockIdx.x >> 1) * 64;
    const int half = blockIdx.x & 1;
    const int lane = tid & 63, w = tid >> 6;
    const int n = lane & 15, q = lane >> 4;

    // early-issue: edges for GEMM1 B-frag
    const int eb = e0 + w * 16;
    f32x4 ex0 = *(const f32x4*)(edges + (size_t)(eb + n) * 32 + q * 8);
    f32x4 ex1 = *(const f32x4*)(edges + (size_t)(eb + n) * 32 + q * 8 + 4);

    // ---------------- Phase B: tmp = feats@basis ----------------------------
    #pragma unroll
    for (int it = 0; it < 8; ++it) {
        int idx = tid + it * 256;                 // 0..2047
        int e = idx >> 5, i = idx & 31;
        f32x3u fv = *(const f32x3u*)(feats + ((size_t)(e0 + e) * 32 + i) * 3);
        const float* bpp = basis + (size_t)(e0 + e) * 27;
        float bp[27];
        #pragma unroll
        for (int v = 0; v < 6; ++v) {
            f32x4u t = *(const f32x4u*)(bpp + v * 4);
            bp[v * 4] = t[0]; bp[v * 4 + 1] = t[1]; bp[v * 4 + 2] = t[2]; bp[v * 4 + 3] = t[3];
        }
        bp[24] = bpp[24]; bp[25] = bpp[25]; bp[26] = bpp[26];
        #pragma unroll
        for (int f = 0; f < 3; ++f) {
            int c = i * 3 + f;
            float v0 = fv[0] * bp[f * 3 + 0] + fv[1] * bp[9 + f * 3 + 0] + fv[2] * bp[18 + f * 3 + 0];
            float v1 = fv[0] * bp[f * 3 + 1] + fv[1] * bp[9 + f * 3 + 1] + fv[2] * bp[18 + f * 3 + 1];
            float v2 = fv[0] * bp[f * 3 + 2] + fv[1] * bp[9 + f * 3 + 2] + fv[2] * bp[18 + f * 3 + 2];
            sh_t01[e * 100 + c] = pkbf(v0, v1);
            sh_t2[e * 104 + c]  = (uint16_t)pkbf(v2, v2);
        }
    }

    // ---------------- Phase C: radial MLP (all 4 waves, 16 edges each) ------
    {
        us8 bx;
        {
            u32x4 bxp;
            bxp[0] = pkbf(ex0[0], ex0[1]); bxp[1] = pkbf(ex0[2], ex0[3]);
            bxp[2] = pkbf(ex1[0], ex1[1]); bxp[3] = pkbf(ex1[2], ex1[3]);
            bx = __builtin_bit_cast(us8, bxp);
        }
        f32x4 acc[4];
        #pragma unroll
        for (int mt = 0; mt < 4; ++mt) {
            us8 a = *(const us8*)(wt + (mt * 16 + n) * 32 + q * 8);
            f32x4 z = {0.f, 0.f, 0.f, 0.f};
            acc[mt] = MFMA(a, bx, z);
        }
        float v[4][4];
        float s1 = 0.f, s2 = 0.f;
        #pragma unroll
        for (int mt = 0; mt < 4; ++mt) {
            f32x4 bb = *(const f32x4*)&b1[mt * 16 + q * 4];
            #pragma unroll
            for (int r = 0; r < 4; ++r) {
                float x = acc[mt][r] + bb[r];
                v[mt][r] = x; s1 += x; s2 += x * x;
            }
        }
        s1 += __shfl_xor(s1, 16, 64); s1 += __shfl_xor(s1, 32, 64);
        s2 += __shfl_xor(s2, 16, 64); s2 += __shfl_xor(s2, 32, 64);
        float mean = s1 * (1.f / 64.f);
        float var  = s2 * (1.f / 64.f) - mean * mean;
        float rs = __builtin_amdgcn_rsqf(var + 1e-5f);
        #pragma unroll
        for (int mt = 0; mt < 4; ++mt) {
            f32x4 gg = *(const f32x4*)&g1[mt * 16 + q * 4];
            f32x4 be = *(const f32x4*)&be1[mt * 16 + q * 4];
            float y0 = gelu_fast((v[mt][0] - mean) * rs * gg[0] + be[0]);
            float y1 = gelu_fast((v[mt][1] - mean) * rs * gg[1] + be[1]);
            float y2 = gelu_fast((v[mt][2] - mean) * rs * gg[2] + be[2]);
            float y3 = gelu_fast((v[mt][3] - mean) * rs * gg[3] + be[3]);
            u32x2 pk; pk[0] = pkbf(y0, y1); pk[1] = pkbf(y2, y3);
            int kq = mt * 2 + (q >> 1);
            *(u32x2*)&sh_h[w][n * 64 + ((kq ^ (n & 7)) << 3) + (q & 1) * 4] = pk;
        }
    }
    // no barrier: sh_h[w] is wave-private until the block barrier below
    {
        us8 bh0 = *(const us8*)&sh_h[w][n * 64 + ((q ^ (n & 7)) << 3)];
        us8 bh1 = *(const us8*)&sh_h[w][n * 64 + (((4 + q) ^ (n & 7)) << 3)];
        f32x4 acc[4];
        #pragma unroll
        for (int mt = 0; mt < 4; ++mt) {
            us8 a0 = *(const us8*)(wt + 2048 + (mt * 16 + n) * 64 + q * 8);
            us8 a1 = *(const us8*)(wt + 2048 + (mt * 16 + n) * 64 + 32 + q * 8);
            f32x4 z = {0.f, 0.f, 0.f, 0.f};
            acc[mt] = MFMA(a0, bh0, z);
            acc[mt] = MFMA(a1, bh1, acc[mt]);
        }
        float v[4][4]; float s1 = 0.f, s2 = 0.f;
        #pragma unroll
        for (int mt = 0; mt < 4; ++mt) {
            f32x4 bb = *(const f32x4*)&b2[mt * 16 + q * 4];
            #pragma unroll
            for (int r = 0; r < 4; ++r) {
                float x = acc[mt][r] + bb[r];
                v[mt][r] = x; s1 += x; s2 += x * x;
            }
        }
        s1 += __shfl_xor(s1, 16, 64); s1 += __shfl_xor(s1, 32, 64);
        s2 += __shfl_xor(s2, 16, 64); s2 += __shfl_xor(s2, 32, 64);
        float mean = s1 * (1.f / 64.f);
        float var  = s2 * (1.f / 64.f) - mean * mean;
        float rs = __builtin_amdgcn_rsqf(var + 1e-5f);
        #pragma unroll
        for (int mt = 0; mt < 4; ++mt) {
            f32x4 gg = *(const f32x4*)&g2[mt * 16 + q * 4];
            f32x4 be = *(const f32x4*)&be2[mt * 16 + q * 4];
            float y0 = gelu_fast((v[mt][0] - mean) * rs * gg[0] + be[0]);
            float y1 = gelu_fast((v[mt][1] - mean) * rs * gg[1] + be[1]);
            float y2 = gelu_fast((v[mt][2] - mean) * rs * gg[2] + be[2]);
            float y3 = gelu_fast((v[mt][3] - mean) * rs * gg[3] + be[3]);
            u32x2 pk; pk[0] = pkbf(y0, y1); pk[1] = pkbf(y2, y3);
            int kq = mt * 2 + (q >> 1);
            // overwrite h1 slot with h2 (same-wave DS ordering; proven)
            *(u32x2*)&sh_h[w][n * 64 + ((kq ^ (n & 7)) << 3) + (q & 1) * 4] = pk;
        }
    }
    __syncthreads();   // the ONLY barrier

    // ---------------- Phase D: rw = h @ W3T fused with c-contraction --------
    // wave w handles o in [half*16 + w*4, +4) over all 64 edges (nt = 0..3),
    // ping-pong pipelined A-loads.
    {
        const uint16_t* w3t = wt + 6144;
        us8 bh[4][2];
        #pragma unroll
        for (int nt = 0; nt < 4; ++nt) {
            bh[nt][0] = *(const us8*)&sh_h[nt][n * 64 + ((q ^ (n & 7)) << 3)];
            bh[nt][1] = *(const us8*)&sh_h[nt][n * 64 + (((4 + q) ^ (n & 7)) << 3)];
        }
        const int ob = half * 16 + w * 4;
        us8 apipe[2][4][2];

#define LOAD_A(dst, mtx) do {                                                  \
        const uint16_t* apb_ = w3t +                                           \
            (size_t)(ob * 96 + (mtx) * 16 + n) * 64 + q * 8;                   \
        _Pragma("unroll")                                                      \
        for (int op_ = 0; op_ < 4; ++op_) {                                    \
            apipe[dst][op_][0] = *(const us8*)(apb_ + (size_t)op_ * 6144);     \
            apipe[dst][op_][1] = *(const us8*)(apb_ + (size_t)op_ * 6144 + 32);\
        }                                                                      \
    } while (0)

        LOAD_A(0, 0);   // prologue

        f32x2 p01[4][4];   // [op][nt] (m0,m1)
        float p2v[4][4];
        #pragma unroll
        for (int op = 0; op < 4; ++op)
            #pragma unroll
            for (int nt = 0; nt < 4; ++nt) {
                p01[op][nt] = (f32x2){0.f, 0.f}; p2v[op][nt] = 0.f;
            }

        #pragma unroll 2   // compile-time ping-pong parity
        for (int mt = 0; mt < 6; ++mt) {
            const int cur = mt & 1, nxt = cur ^ 1;
            if (mt < 5) LOAD_A(nxt, mt + 1);
            #pragma unroll
            for (int nt = 0; nt < 4; ++nt) {
                int e = nt * 16 + n;
                u32x4 d  = *(const u32x4*)&sh_t01[e * 100 + mt * 16 + q * 4];
                us4 t2   = *(const us4*)&sh_t2[e * 104 + mt * 16 + q * 4];
                f32x2 f01[4]; float fm2[4];
                #pragma unroll
                for (int r = 0; r < 4; ++r) {
                    f01[r] = up01(d[r]);
                    fm2[r] = b2f(t2[r]);
                }
                #pragma unroll
                for (int op = 0; op < 4; ++op) {
                    f32x4 z = {0.f, 0.f, 0.f, 0.f};
                    f32x4 acc = MFMA(apipe[cur][op][0], bh[nt][0], z);
                    acc = MFMA(apipe[cur][op][1], bh[nt][1], acc);
                    #pragma unroll
                    for (int r = 0; r < 4; ++r) {
                        p01[op][nt] += f01[r] * acc[r];   // v_pk_fma_f32
                        p2v[op][nt] += fm2[r] * acc[r];
                    }
                }
            }
        }
#undef LOAD_A
        // reduce over q (xor 16, 32) and store
        #pragma unroll
        for (int nt = 0; nt < 4; ++nt) {
            #pragma unroll
            for (int op = 0; op < 4; ++op) {
                int o = ob + op;
                float v0 = p01[op][nt][0], v1 = p01[op][nt][1], v2 = p2v[op][nt];
                v0 += __shfl_xor(v0, 16, 64); v0 += __shfl_xor(v0, 32, 64);
                v1 += __shfl_xor(v1, 16, 64); v1 += __shfl_xor(v1, 32, 64);
                v2 += __shfl_xor(v2, 16, 64); v2 += __shfl_xor(v2, 32, 64);
                float val = (q == 0) ? v0 : ((q == 1) ? v1 : v2);
                if (q < 3)
                    out[(size_t)(e0 + nt * 16 + n) * 96 + o * 3 + q] = val;
            }
        }
    }
}

// ---- launch ----------------------------------------------------------------
extern "C" void kernel_launch(void* const* d_in, const int* in_sizes, int n_in,
                              void* d_out, int out_size, void* d_ws, size_t ws_size,
                              hipStream_t stream) {
    const float* edges = (const float*)d_in[0];
    const float* feats = (const float*)d_in[1];
    const float* basis = (const float*)d_in[2];
    const float* W1  = (const float*)d_in[3];
    const float* b1  = (const float*)d_in[4];
    const float* g1  = (const float*)d_in[5];
    const float* be1 = (const float*)d_in[6];
    const float* W2  = (const float*)d_in[7];
    const float* b2  = (const float*)d_in[8];
    const float* g2  = (const float*)d_in[9];
    const float* be2 = (const float*)d_in[10];
    const float* W3  = (const float*)d_in[11];
    uint16_t* wt = (uint16_t*)d_ws;           // 202752 uint16 = 405504 B
    float* out = (float*)d_out;

    const int E = in_sizes[0] / 32;           // 32768
    hipLaunchKernelGGL(prep_weights, dim3(216), dim3(256), 0, stream, W1, W2, W3, wt);
    hipLaunchKernelGGL(pairconv_main, dim3((E / 64) * 2), dim3(256), 0, stream,
                       edges, feats, basis, b1, g1, be1, b2, g2, be2, wt, out);
}

// Round 8
// 166.952 us; speedup vs baseline: 1.2847x; 1.2847x over previous
//
#include <hip/hip_runtime.h>
#include <cstdint>
#include <cstddef>

// ---- types ----------------------------------------------------------------
typedef __bf16 bf8 __attribute__((ext_vector_type(8)));
typedef float f32x4 __attribute__((ext_vector_type(4)));
typedef float f32x2 __attribute__((ext_vector_type(2)));
typedef float f32x4u __attribute__((ext_vector_type(4), aligned(4)));
typedef unsigned short us8 __attribute__((ext_vector_type(8)));
typedef unsigned short us4 __attribute__((ext_vector_type(4)));
typedef unsigned int u32x4 __attribute__((ext_vector_type(4)));
typedef unsigned int u32x2 __attribute__((ext_vector_type(2)));

__device__ __forceinline__ uint16_t f2b(float f) {
    uint32_t u = __builtin_bit_cast(uint32_t, f);
    u += 0x7FFFu + ((u >> 16) & 1u);          // RNE
    return (uint16_t)(u >> 16);
}
__device__ __forceinline__ float b2f(uint16_t h) {
    uint32_t u = ((uint32_t)h) << 16;
    return __builtin_bit_cast(float, u);
}
#if __has_builtin(__builtin_amdgcn_cvt_pk_bf16_f32)
__device__ __forceinline__ uint32_t pkbf(float a, float b) {
    auto r = __builtin_amdgcn_cvt_pk_bf16_f32(a, b);
    return __builtin_bit_cast(uint32_t, r);
}
#else
__device__ __forceinline__ uint32_t pkbf(float a, float b) {
    return (uint32_t)f2b(a) | ((uint32_t)f2b(b) << 16);
}
#endif
__device__ __forceinline__ f32x2 up01(uint32_t d) {
    f32x2 r;
    r[0] = __builtin_bit_cast(float, d << 16);
    r[1] = __builtin_bit_cast(float, d & 0xffff0000u);
    return r;
}
__device__ __forceinline__ float gelu_fast(float y) {
    float y3 = y * y * y;
    float z2 = 1.5957691216f * (y + 0.044715f * y3);
    float u = __expf(-z2);
    return y * __builtin_amdgcn_rcpf(1.0f + u);
}

#define MFMA(a, b, c) __builtin_amdgcn_mfma_f32_16x16x32_bf16( \
    __builtin_bit_cast(bf8, (a)), __builtin_bit_cast(bf8, (b)), (c), 0, 0, 0)

// ws layout (uint16_t): w1t[64][32] @0, w2t[64][64] @2048, w3t[3072][64] @6144,
// h_g[32768][64] @202752 (4 MiB)
#define H_OFF 202752

// ---- prep: cast+transpose weights into ws ---------------------------------
__global__ void prep_weights(const float* __restrict__ W1,
                             const float* __restrict__ W2,
                             const float* __restrict__ W3,
                             uint16_t* __restrict__ wt) {
    __shared__ float tile[32][33];
    int bx = blockIdx.x;
    if (bx < 192) {
        int kb = (bx & 1) * 32;
        int jb = (bx >> 1) * 32;
        int tx = threadIdx.x & 31, ty = threadIdx.x >> 5;   // 32 x 8
        #pragma unroll
        for (int l = 0; l < 4; ++l)
            tile[ty + 8 * l][tx] = W3[(size_t)(kb + ty + 8 * l) * 3072 + jb + tx];
        __syncthreads();
        #pragma unroll
        for (int l = 0; l < 4; ++l) {
            int j = jb + ty + 8 * l;
            wt[6144 + (size_t)j * 64 + kb + tx] = f2b(tile[tx][ty + 8 * l]);
        }
    } else {
        int t = (bx - 192) * 256 + threadIdx.x;   // 0..6143
        if (t < 2048) {                            // W1: [32][64]
            int i = t >> 6, j = t & 63;
            wt[j * 32 + i] = f2b(W1[t]);
        } else {                                   // W2: [64][64]
            int t2 = t - 2048;
            int k = t2 >> 6, j = t2 & 63;
            wt[2048 + j * 64 + k] = f2b(W2[t2]);
        }
    }
}

// ---- kernel 1: radial MLP -> h_g (global, bf16 [e][64]) --------------------
// 2048 blocks x 64 threads = 1 wave = 16 edges. No barriers (wave-private LDS).
__global__ __launch_bounds__(64) void mlp_kernel(
    const float* __restrict__ edges,
    const float* __restrict__ b1, const float* __restrict__ g1, const float* __restrict__ be1,
    const float* __restrict__ b2, const float* __restrict__ g2, const float* __restrict__ be2,
    const uint16_t* __restrict__ wt, uint16_t* __restrict__ h_g) {

    __shared__ __align__(16) uint16_t sh_h1[16 * 64];   // 2 KiB, wave-private

    const int lane = threadIdx.x;
    const int n = lane & 15, q = lane >> 4;
    const int eb = blockIdx.x * 16;

    f32x4 ex0 = *(const f32x4*)(edges + (size_t)(eb + n) * 32 + q * 8);
    f32x4 ex1 = *(const f32x4*)(edges + (size_t)(eb + n) * 32 + q * 8 + 4);

    // GEMM1
    us8 bx;
    {
        u32x4 bxp;
        bxp[0] = pkbf(ex0[0], ex0[1]); bxp[1] = pkbf(ex0[2], ex0[3]);
        bxp[2] = pkbf(ex1[0], ex1[1]); bxp[3] = pkbf(ex1[2], ex1[3]);
        bx = __builtin_bit_cast(us8, bxp);
    }
    {
        f32x4 acc[4];
        #pragma unroll
        for (int mt = 0; mt < 4; ++mt) {
            us8 a = *(const us8*)(wt + (mt * 16 + n) * 32 + q * 8);
            f32x4 z = {0.f, 0.f, 0.f, 0.f};
            acc[mt] = MFMA(a, bx, z);
        }
        float v[4][4]; float s1 = 0.f, s2 = 0.f;
        #pragma unroll
        for (int mt = 0; mt < 4; ++mt) {
            f32x4 bb = *(const f32x4*)&b1[mt * 16 + q * 4];
            #pragma unroll
            for (int r = 0; r < 4; ++r) {
                float x = acc[mt][r] + bb[r];
                v[mt][r] = x; s1 += x; s2 += x * x;
            }
        }
        s1 += __shfl_xor(s1, 16, 64); s1 += __shfl_xor(s1, 32, 64);
        s2 += __shfl_xor(s2, 16, 64); s2 += __shfl_xor(s2, 32, 64);
        float mean = s1 * (1.f / 64.f);
        float var  = s2 * (1.f / 64.f) - mean * mean;
        float rs = __builtin_amdgcn_rsqf(var + 1e-5f);
        #pragma unroll
        for (int mt = 0; mt < 4; ++mt) {
            f32x4 gg = *(const f32x4*)&g1[mt * 16 + q * 4];
            f32x4 be = *(const f32x4*)&be1[mt * 16 + q * 4];
            float y0 = gelu_fast((v[mt][0] - mean) * rs * gg[0] + be[0]);
            float y1 = gelu_fast((v[mt][1] - mean) * rs * gg[1] + be[1]);
            float y2 = gelu_fast((v[mt][2] - mean) * rs * gg[2] + be[2]);
            float y3 = gelu_fast((v[mt][3] - mean) * rs * gg[3] + be[3]);
            u32x2 pk; pk[0] = pkbf(y0, y1); pk[1] = pkbf(y2, y3);
            int kq = mt * 2 + (q >> 1);
            *(u32x2*)&sh_h1[n * 64 + ((kq ^ (n & 7)) << 3) + (q & 1) * 4] = pk;
        }
    }
    // GEMM2 (same-wave DS ordering; no barrier)
    {
        us8 bh0 = *(const us8*)&sh_h1[n * 64 + ((q ^ (n & 7)) << 3)];
        us8 bh1 = *(const us8*)&sh_h1[n * 64 + (((4 + q) ^ (n & 7)) << 3)];
        f32x4 acc[4];
        #pragma unroll
        for (int mt = 0; mt < 4; ++mt) {
            us8 a0 = *(const us8*)(wt + 2048 + (mt * 16 + n) * 64 + q * 8);
            us8 a1 = *(const us8*)(wt + 2048 + (mt * 16 + n) * 64 + 32 + q * 8);
            f32x4 z = {0.f, 0.f, 0.f, 0.f};
            acc[mt] = MFMA(a0, bh0, z);
            acc[mt] = MFMA(a1, bh1, acc[mt]);
        }
        float v[4][4]; float s1 = 0.f, s2 = 0.f;
        #pragma unroll
        for (int mt = 0; mt < 4; ++mt) {
            f32x4 bb = *(const f32x4*)&b2[mt * 16 + q * 4];
            #pragma unroll
            for (int r = 0; r < 4; ++r) {
                float x = acc[mt][r] + bb[r];
                v[mt][r] = x; s1 += x; s2 += x * x;
            }
        }
        s1 += __shfl_xor(s1, 16, 64); s1 += __shfl_xor(s1, 32, 64);
        s2 += __shfl_xor(s2, 16, 64); s2 += __shfl_xor(s2, 32, 64);
        float mean = s1 * (1.f / 64.f);
        float var  = s2 * (1.f / 64.f) - mean * mean;
        float rs = __builtin_amdgcn_rsqf(var + 1e-5f);
        #pragma unroll
        for (int mt = 0; mt < 4; ++mt) {
            f32x4 gg = *(const f32x4*)&g2[mt * 16 + q * 4];
            f32x4 be = *(const f32x4*)&be2[mt * 16 + q * 4];
            float y0 = gelu_fast((v[mt][0] - mean) * rs * gg[0] + be[0]);
            float y1 = gelu_fast((v[mt][1] - mean) * rs * gg[1] + be[1]);
            float y2 = gelu_fast((v[mt][2] - mean) * rs * gg[2] + be[2]);
            float y3 = gelu_fast((v[mt][3] - mean) * rs * gg[3] + be[3]);
            u32x2 pk; pk[0] = pkbf(y0, y1); pk[1] = pkbf(y2, y3);
            // h_g[e][k] linear, k = mt*16 + q*4 .. +4  (8-B aligned store)
            *(u32x2*)(h_g + (size_t)(eb + n) * 64 + mt * 16 + q * 4) = pk;
        }
    }
}

// ---- kernel 2: tmp (phase B) + conv (phase D) ------------------------------
// grid 1024 = 512 edge-groups x 2 o-halves; 256 thr (4 waves); 16 waves/CU.
// Phase B: thread = (e = tid>>2, iq = tid&3); 13 coalesced VMEM loads up
// front, 216 fma, vector ds_writes. Phase D: wave w -> o in
// [half*16 + w*4, +4), nt=0..3, 6 mt steps; h from global (L1-cached).
// Out staged in LDS -> contiguous 192 B/edge stores.
__global__ __launch_bounds__(256, 4) void conv_kernel(
    const float* __restrict__ feats, const float* __restrict__ basis,
    const uint16_t* __restrict__ wt, const uint16_t* __restrict__ h_g,
    float* __restrict__ out) {

    __shared__ __align__(16) uint32_t sh_t01[64 * 100];   // 25.0 KiB
    __shared__ __align__(16) uint16_t sh_t2[64 * 104];    // 13.0 KiB (reused for out)

    const int tid = threadIdx.x;
    const int e0 = (blockIdx.x >> 1) * 64;
    const int half = blockIdx.x & 1;

    // ---------------- Phase B ----------------------------------------------
    {
        const int e = tid >> 2, iq = tid & 3;
        // feats: 96 B contiguous per thread, perfectly coalesced
        f32x4 fv[6];
        const float* fp = feats + (size_t)(e0 + e) * 96 + iq * 24;
        #pragma unroll
        for (int l = 0; l < 6; ++l) fv[l] = *(const f32x4*)(fp + l * 4);
        // basis: 27 floats (4x redundant across iq, L1-absorbed)
        float bp[27];
        const float* bpp = basis + (size_t)(e0 + e) * 27;
        #pragma unroll
        for (int v = 0; v < 6; ++v) {
            f32x4u t = *(const f32x4u*)(bpp + v * 4);
            bp[v * 4] = t[0]; bp[v * 4 + 1] = t[1]; bp[v * 4 + 2] = t[2]; bp[v * 4 + 3] = t[3];
        }
        bp[24] = bpp[24]; bp[25] = bpp[25]; bp[26] = bpp[26];

        uint32_t t01b[24]; uint16_t t2b[24];
        const float* fvs = (const float*)fv;   // 24 floats = 8 i x 3
        #pragma unroll
        for (int ii = 0; ii < 8; ++ii) {
            float a0 = fvs[ii * 3], a1 = fvs[ii * 3 + 1], a2 = fvs[ii * 3 + 2];
            #pragma unroll
            for (int f = 0; f < 3; ++f) {
                float v0 = a0 * bp[f * 3 + 0] + a1 * bp[9 + f * 3 + 0] + a2 * bp[18 + f * 3 + 0];
                float v1 = a0 * bp[f * 3 + 1] + a1 * bp[9 + f * 3 + 1] + a2 * bp[18 + f * 3 + 1];
                float v2 = a0 * bp[f * 3 + 2] + a1 * bp[9 + f * 3 + 2] + a2 * bp[18 + f * 3 + 2];
                t01b[ii * 3 + f] = pkbf(v0, v1);
                t2b[ii * 3 + f]  = (uint16_t)pkbf(v2, v2);
            }
        }
        // vector LDS stores (bank-verified 2-way max)
        #pragma unroll
        for (int l = 0; l < 6; ++l)
            *(u32x4*)&sh_t01[e * 100 + iq * 24 + l * 4] = *(u32x4*)&t01b[l * 4];
        #pragma unroll
        for (int l = 0; l < 3; ++l)
            *(us8*)&sh_t2[e * 104 + iq * 24 + l * 8] = *(us8*)&t2b[l * 8];
    }
    __syncthreads();   // barrier 1: tmp ready

    // ---------------- Phase D ----------------------------------------------
    const int lane = tid & 63, w = tid >> 6;
    const int n = lane & 15, q = lane >> 4;
    {
        const uint16_t* w3t = wt + 6144;
        us8 bh[4][2];
        #pragma unroll
        for (int nt = 0; nt < 4; ++nt) {
            const uint16_t* hp = h_g + (size_t)(e0 + nt * 16 + n) * 64 + q * 8;
            bh[nt][0] = *(const us8*)hp;
            bh[nt][1] = *(const us8*)(hp + 32);
        }
        const int ob = half * 16 + w * 4;
        f32x2 p01[4][4];   // [op][nt]
        float p2v[4][4];
        #pragma unroll
        for (int op = 0; op < 4; ++op)
            #pragma unroll
            for (int nt = 0; nt < 4; ++nt) {
                p01[op][nt] = (f32x2){0.f, 0.f}; p2v[op][nt] = 0.f;
            }

        #pragma unroll 1
        for (int mt = 0; mt < 6; ++mt) {
            us8 a[4][2];
            const uint16_t* apb = w3t + (size_t)(ob * 96 + mt * 16 + n) * 64 + q * 8;
            #pragma unroll
            for (int op = 0; op < 4; ++op) {
                a[op][0] = *(const us8*)(apb + (size_t)op * 6144);
                a[op][1] = *(const us8*)(apb + (size_t)op * 6144 + 32);
            }
            #pragma unroll
            for (int nt = 0; nt < 4; ++nt) {
                int e = nt * 16 + n;
                u32x4 d  = *(const u32x4*)&sh_t01[e * 100 + mt * 16 + q * 4];
                us4 t2   = *(const us4*)&sh_t2[e * 104 + mt * 16 + q * 4];
                f32x2 f01[4]; float fm2[4];
                #pragma unroll
                for (int r = 0; r < 4; ++r) {
                    f01[r] = up01(d[r]);
                    fm2[r] = b2f(t2[r]);
                }
                #pragma unroll
                for (int op = 0; op < 4; ++op) {
                    f32x4 z = {0.f, 0.f, 0.f, 0.f};
                    f32x4 acc = MFMA(a[op][0], bh[nt][0], z);
                    acc = MFMA(a[op][1], bh[nt][1], acc);
                    #pragma unroll
                    for (int r = 0; r < 4; ++r) {
                        p01[op][nt] += f01[r] * acc[r];   // v_pk_fma_f32
                        p2v[op][nt] += fm2[r] * acc[r];
                    }
                }
            }
        }

        __syncthreads();   // barrier 2: all tmp reads done, sh_t2 reusable
        float* shout = (float*)sh_t2;   // [64][52] floats, 13312 B
        #pragma unroll
        for (int nt = 0; nt < 4; ++nt) {
            #pragma unroll
            for (int op = 0; op < 4; ++op) {
                float v0 = p01[op][nt][0], v1 = p01[op][nt][1], v2 = p2v[op][nt];
                v0 += __shfl_xor(v0, 16, 64); v0 += __shfl_xor(v0, 32, 64);
                v1 += __shfl_xor(v1, 16, 64); v1 += __shfl_xor(v1, 32, 64);
                v2 += __shfl_xor(v2, 16, 64); v2 += __shfl_xor(v2, 32, 64);
                float val = (q == 0) ? v0 : ((q == 1) ? v1 : v2);
                if (q < 3)
                    shout[(nt * 16 + n) * 52 + (w * 4 + op) * 3 + q] = val;
            }
        }
    }
    __syncthreads();   // barrier 3: shout complete

    // coalesced dump: 192 B contiguous per edge-half
    {
        const float* shout = (const float*)sh_t2;
        int e = tid >> 2, j0 = (tid & 3) * 12;
        float* op = out + (size_t)(e0 + e) * 96 + half * 48 + j0;
        #pragma unroll
        for (int l = 0; l < 3; ++l) {
            f32x4 v = *(const f32x4*)&shout[e * 52 + j0 + l * 4];
            *(f32x4*)(op + l * 4) = v;
        }
    }
}

// ---- launch ----------------------------------------------------------------
extern "C" void kernel_launch(void* const* d_in, const int* in_sizes, int n_in,
                              void* d_out, int out_size, void* d_ws, size_t ws_size,
                              hipStream_t stream) {
    const float* edges = (const float*)d_in[0];
    const float* feats = (const float*)d_in[1];
    const float* basis = (const float*)d_in[2];
    const float* W1  = (const float*)d_in[3];
    const float* b1  = (const float*)d_in[4];
    const float* g1  = (const float*)d_in[5];
    const float* be1 = (const float*)d_in[6];
    const float* W2  = (const float*)d_in[7];
    const float* b2  = (const float*)d_in[8];
    const float* g2  = (const float*)d_in[9];
    const float* be2 = (const float*)d_in[10];
    const float* W3  = (const float*)d_in[11];
    uint16_t* wt  = (uint16_t*)d_ws;          // 405504 B weights + 4 MiB h_g
    uint16_t* h_g = wt + H_OFF;
    float* out = (float*)d_out;

    const int E = in_sizes[0] / 32;           // 32768
    hipLaunchKernelGGL(prep_weights, dim3(216), dim3(256), 0, stream, W1, W2, W3, wt);
    hipLaunchKernelGGL(mlp_kernel, dim3(E / 16), dim3(64), 0, stream,
                       edges, b1, g1, be1, b2, g2, be2, wt, h_g);
    hipLaunchKernelGGL(conv_kernel, dim3((E / 64) * 2), dim3(256), 0, stream,
                       feats, basis, wt, h_g, out);
}

// Round 9
// 145.650 us; speedup vs baseline: 1.4726x; 1.1463x over previous
//
#include <hip/hip_runtime.h>
#include <cstdint>
#include <cstddef>

// ---- types ----------------------------------------------------------------
typedef __bf16 bf8 __attribute__((ext_vector_type(8)));
typedef float f32x4 __attribute__((ext_vector_type(4)));
typedef float f32x2 __attribute__((ext_vector_type(2)));
typedef float f32x4u __attribute__((ext_vector_type(4), aligned(4)));
typedef unsigned short us8 __attribute__((ext_vector_type(8)));
typedef unsigned short us4 __attribute__((ext_vector_type(4)));
typedef unsigned int u32x4 __attribute__((ext_vector_type(4)));
typedef unsigned int u32x2 __attribute__((ext_vector_type(2)));

__device__ __forceinline__ uint16_t f2b(float f) {
    uint32_t u = __builtin_bit_cast(uint32_t, f);
    u += 0x7FFFu + ((u >> 16) & 1u);          // RNE
    return (uint16_t)(u >> 16);
}
__device__ __forceinline__ float b2f(uint16_t h) {
    uint32_t u = ((uint32_t)h) << 16;
    return __builtin_bit_cast(float, u);
}
#if __has_builtin(__builtin_amdgcn_cvt_pk_bf16_f32)
__device__ __forceinline__ uint32_t pkbf(float a, float b) {
    auto r = __builtin_amdgcn_cvt_pk_bf16_f32(a, b);
    return __builtin_bit_cast(uint32_t, r);
}
#else
__device__ __forceinline__ uint32_t pkbf(float a, float b) {
    return (uint32_t)f2b(a) | ((uint32_t)f2b(b) << 16);
}
#endif
__device__ __forceinline__ f32x2 up01(uint32_t d) {
    f32x2 r;
    r[0] = __builtin_bit_cast(float, d << 16);
    r[1] = __builtin_bit_cast(float, d & 0xffff0000u);
    return r;
}
__device__ __forceinline__ float gelu_fast(float y) {
    float y3 = y * y * y;
    float z2 = 1.5957691216f * (y + 0.044715f * y3);
    float u = __expf(-z2);
    return y * __builtin_amdgcn_rcpf(1.0f + u);
}

#define MFMA(a, b, c) __builtin_amdgcn_mfma_f32_16x16x32_bf16( \
    __builtin_bit_cast(bf8, (a)), __builtin_bit_cast(bf8, (b)), (c), 0, 0, 0)

// ws layout (uint16_t): w1t[64][32] @0, w2t[64][64] @2048, w3t[3072][64] @6144,
// h_g[32768][64] @202752 (4 MiB)
#define H_OFF 202752

// ---- prep: cast+transpose weights into ws ---------------------------------
__global__ void prep_weights(const float* __restrict__ W1,
                             const float* __restrict__ W2,
                             const float* __restrict__ W3,
                             uint16_t* __restrict__ wt) {
    __shared__ float tile[32][33];
    int bx = blockIdx.x;
    if (bx < 192) {
        int kb = (bx & 1) * 32;
        int jb = (bx >> 1) * 32;
        int tx = threadIdx.x & 31, ty = threadIdx.x >> 5;   // 32 x 8
        #pragma unroll
        for (int l = 0; l < 4; ++l)
            tile[ty + 8 * l][tx] = W3[(size_t)(kb + ty + 8 * l) * 3072 + jb + tx];
        __syncthreads();
        #pragma unroll
        for (int l = 0; l < 4; ++l) {
            int j = jb + ty + 8 * l;
            wt[6144 + (size_t)j * 64 + kb + tx] = f2b(tile[tx][ty + 8 * l]);
        }
    } else {
        int t = (bx - 192) * 256 + threadIdx.x;   // 0..6143
        if (t < 2048) {                            // W1: [32][64]
            int i = t >> 6, j = t & 63;
            wt[j * 32 + i] = f2b(W1[t]);
        } else {                                   // W2: [64][64]
            int t2 = t - 2048;
            int k = t2 >> 6, j = t2 & 63;
            wt[2048 + j * 64 + k] = f2b(W2[t2]);
        }
    }
}

// ---- kernel 1: radial MLP -> h_g (global, bf16 [e][64]) --------------------
// 2048 blocks x 64 threads = 1 wave = 16 edges. No barriers (wave-private LDS).
__global__ __launch_bounds__(64) void mlp_kernel(
    const float* __restrict__ edges,
    const float* __restrict__ b1, const float* __restrict__ g1, const float* __restrict__ be1,
    const float* __restrict__ b2, const float* __restrict__ g2, const float* __restrict__ be2,
    const uint16_t* __restrict__ wt, uint16_t* __restrict__ h_g) {

    __shared__ __align__(16) uint16_t sh_h1[16 * 64];   // 2 KiB, wave-private

    const int lane = threadIdx.x;
    const int n = lane & 15, q = lane >> 4;
    const int eb = blockIdx.x * 16;

    f32x4 ex0 = *(const f32x4*)(edges + (size_t)(eb + n) * 32 + q * 8);
    f32x4 ex1 = *(const f32x4*)(edges + (size_t)(eb + n) * 32 + q * 8 + 4);

    // GEMM1
    us8 bx;
    {
        u32x4 bxp;
        bxp[0] = pkbf(ex0[0], ex0[1]); bxp[1] = pkbf(ex0[2], ex0[3]);
        bxp[2] = pkbf(ex1[0], ex1[1]); bxp[3] = pkbf(ex1[2], ex1[3]);
        bx = __builtin_bit_cast(us8, bxp);
    }
    {
        f32x4 acc[4];
        #pragma unroll
        for (int mt = 0; mt < 4; ++mt) {
            us8 a = *(const us8*)(wt + (mt * 16 + n) * 32 + q * 8);
            f32x4 z = {0.f, 0.f, 0.f, 0.f};
            acc[mt] = MFMA(a, bx, z);
        }
        float v[4][4]; float s1 = 0.f, s2 = 0.f;
        #pragma unroll
        for (int mt = 0; mt < 4; ++mt) {
            f32x4 bb = *(const f32x4*)&b1[mt * 16 + q * 4];
            #pragma unroll
            for (int r = 0; r < 4; ++r) {
                float x = acc[mt][r] + bb[r];
                v[mt][r] = x; s1 += x; s2 += x * x;
            }
        }
        s1 += __shfl_xor(s1, 16, 64); s1 += __shfl_xor(s1, 32, 64);
        s2 += __shfl_xor(s2, 16, 64); s2 += __shfl_xor(s2, 32, 64);
        float mean = s1 * (1.f / 64.f);
        float var  = s2 * (1.f / 64.f) - mean * mean;
        float rs = __builtin_amdgcn_rsqf(var + 1e-5f);
        #pragma unroll
        for (int mt = 0; mt < 4; ++mt) {
            f32x4 gg = *(const f32x4*)&g1[mt * 16 + q * 4];
            f32x4 be = *(const f32x4*)&be1[mt * 16 + q * 4];
            float y0 = gelu_fast((v[mt][0] - mean) * rs * gg[0] + be[0]);
            float y1 = gelu_fast((v[mt][1] - mean) * rs * gg[1] + be[1]);
            float y2 = gelu_fast((v[mt][2] - mean) * rs * gg[2] + be[2]);
            float y3 = gelu_fast((v[mt][3] - mean) * rs * gg[3] + be[3]);
            u32x2 pk; pk[0] = pkbf(y0, y1); pk[1] = pkbf(y2, y3);
            int kq = mt * 2 + (q >> 1);
            *(u32x2*)&sh_h1[n * 64 + ((kq ^ (n & 7)) << 3) + (q & 1) * 4] = pk;
        }
    }
    // GEMM2 (same-wave DS ordering; no barrier)
    {
        us8 bh0 = *(const us8*)&sh_h1[n * 64 + ((q ^ (n & 7)) << 3)];
        us8 bh1 = *(const us8*)&sh_h1[n * 64 + (((4 + q) ^ (n & 7)) << 3)];
        f32x4 acc[4];
        #pragma unroll
        for (int mt = 0; mt < 4; ++mt) {
            us8 a0 = *(const us8*)(wt + 2048 + (mt * 16 + n) * 64 + q * 8);
            us8 a1 = *(const us8*)(wt + 2048 + (mt * 16 + n) * 64 + 32 + q * 8);
            f32x4 z = {0.f, 0.f, 0.f, 0.f};
            acc[mt] = MFMA(a0, bh0, z);
            acc[mt] = MFMA(a1, bh1, acc[mt]);
        }
        float v[4][4]; float s1 = 0.f, s2 = 0.f;
        #pragma unroll
        for (int mt = 0; mt < 4; ++mt) {
            f32x4 bb = *(const f32x4*)&b2[mt * 16 + q * 4];
            #pragma unroll
            for (int r = 0; r < 4; ++r) {
                float x = acc[mt][r] + bb[r];
                v[mt][r] = x; s1 += x; s2 += x * x;
            }
        }
        s1 += __shfl_xor(s1, 16, 64); s1 += __shfl_xor(s1, 32, 64);
        s2 += __shfl_xor(s2, 16, 64); s2 += __shfl_xor(s2, 32, 64);
        float mean = s1 * (1.f / 64.f);
        float var  = s2 * (1.f / 64.f) - mean * mean;
        float rs = __builtin_amdgcn_rsqf(var + 1e-5f);
        #pragma unroll
        for (int mt = 0; mt < 4; ++mt) {
            f32x4 gg = *(const f32x4*)&g2[mt * 16 + q * 4];
            f32x4 be = *(const f32x4*)&be2[mt * 16 + q * 4];
            float y0 = gelu_fast((v[mt][0] - mean) * rs * gg[0] + be[0]);
            float y1 = gelu_fast((v[mt][1] - mean) * rs * gg[1] + be[1]);
            float y2 = gelu_fast((v[mt][2] - mean) * rs * gg[2] + be[2]);
            float y3 = gelu_fast((v[mt][3] - mean) * rs * gg[3] + be[3]);
            u32x2 pk; pk[0] = pkbf(y0, y1); pk[1] = pkbf(y2, y3);
            *(u32x2*)(h_g + (size_t)(eb + n) * 64 + mt * 16 + q * 4) = pk;
        }
    }
}

// ---- kernel 2: tmp (phase B) + conv (phase D) ------------------------------
// 1024 blocks x 256 thr (4 waves), 32 edges/block, FULL 32 o per block.
// Wave w -> o in [w*8, +8) (2 oc-chunks of 4), nt=0..1 edge-subtiles.
// -> 4096 waves = 16 waves/CU (grid 4 blocks/CU, LDS 31.5 KiB, VGPR<=128).
// Each out row (384 B) written whole by ONE block -> clean writes; feats/
// basis/h read exactly once per edge; w3t stays L2-resident (384 KiB).
__global__ __launch_bounds__(256, 4) void conv_kernel(
    const float* __restrict__ feats, const float* __restrict__ basis,
    const uint16_t* __restrict__ wt, const uint16_t* __restrict__ h_g,
    float* __restrict__ out) {

    __shared__ __align__(16) uint32_t sh_t01[32 * 100];   // 12.5 KiB (m0,m1)
    __shared__ __align__(16) uint16_t sh_t2[32 * 104];    // 6.5 KiB (m2)
    __shared__ __align__(16) float sh_out[32 * 100];      // 12.5 KiB

    const int tid = threadIdx.x;
    const int e0 = blockIdx.x * 32;

    // ---------------- Phase B: tmp = feats@basis ----------------------------
    {
        const int e = tid >> 3, sub = tid & 7;   // 32 edges x 8 subs (4 i each)
        f32x4 fv[3];
        const float* fp = feats + (size_t)(e0 + e) * 96 + sub * 12;
        #pragma unroll
        for (int l = 0; l < 3; ++l) fv[l] = *(const f32x4u*)(fp + l * 4);
        float bp[27];
        const float* bpp = basis + (size_t)(e0 + e) * 27;
        #pragma unroll
        for (int v = 0; v < 6; ++v) {
            f32x4u t = *(const f32x4u*)(bpp + v * 4);
            bp[v * 4] = t[0]; bp[v * 4 + 1] = t[1]; bp[v * 4 + 2] = t[2]; bp[v * 4 + 3] = t[3];
        }
        bp[24] = bpp[24]; bp[25] = bpp[25]; bp[26] = bpp[26];

        uint32_t t01b[12]; uint16_t t2b[12];
        const float* fvs = (const float*)fv;   // 12 floats = 4 i x 3
        #pragma unroll
        for (int ii = 0; ii < 4; ++ii) {
            float a0 = fvs[ii * 3], a1 = fvs[ii * 3 + 1], a2 = fvs[ii * 3 + 2];
            #pragma unroll
            for (int f = 0; f < 3; ++f) {
                float v0 = a0 * bp[f * 3 + 0] + a1 * bp[9 + f * 3 + 0] + a2 * bp[18 + f * 3 + 0];
                float v1 = a0 * bp[f * 3 + 1] + a1 * bp[9 + f * 3 + 1] + a2 * bp[18 + f * 3 + 1];
                float v2 = a0 * bp[f * 3 + 2] + a1 * bp[9 + f * 3 + 2] + a2 * bp[18 + f * 3 + 2];
                t01b[ii * 3 + f] = pkbf(v0, v1);
                t2b[ii * 3 + f]  = (uint16_t)pkbf(v2, v2);
            }
        }
        const int c0 = sub * 12;
        #pragma unroll
        for (int l = 0; l < 3; ++l)
            *(u32x4*)&sh_t01[e * 100 + c0 + l * 4] = *(u32x4*)&t01b[l * 4];
        #pragma unroll
        for (int l = 0; l < 3; ++l)
            *(us4*)&sh_t2[e * 104 + c0 + l * 4] = *(us4*)&t2b[l * 4];
    }
    __syncthreads();   // barrier 1: tmp ready

    // ---------------- Phase D ----------------------------------------------
    const int lane = tid & 63, w = tid >> 6;
    const int n = lane & 15, q = lane >> 4;
    {
        const uint16_t* w3t = wt + 6144;
        us8 bh[2][2];
        #pragma unroll
        for (int nt = 0; nt < 2; ++nt) {
            const uint16_t* hp = h_g + (size_t)(e0 + nt * 16 + n) * 64 + q * 8;
            bh[nt][0] = *(const us8*)hp;
            bh[nt][1] = *(const us8*)(hp + 32);
        }
        #pragma unroll 1
        for (int oc = 0; oc < 2; ++oc) {
            const int ob2 = w * 8 + oc * 4;
            f32x2 p01[4][2];   // [op][nt]
            float p2v[4][2];
            #pragma unroll
            for (int op = 0; op < 4; ++op)
                #pragma unroll
                for (int nt = 0; nt < 2; ++nt) {
                    p01[op][nt] = (f32x2){0.f, 0.f}; p2v[op][nt] = 0.f;
                }

            #pragma unroll 1
            for (int mt = 0; mt < 6; ++mt) {
                us8 a[4][2];
                const uint16_t* apb = w3t + (size_t)(ob2 * 96 + mt * 16 + n) * 64 + q * 8;
                #pragma unroll
                for (int op = 0; op < 4; ++op) {
                    a[op][0] = *(const us8*)(apb + (size_t)op * 6144);
                    a[op][1] = *(const us8*)(apb + (size_t)op * 6144 + 32);
                }
                #pragma unroll
                for (int nt = 0; nt < 2; ++nt) {
                    int e = nt * 16 + n;
                    u32x4 d  = *(const u32x4*)&sh_t01[e * 100 + mt * 16 + q * 4];
                    us4 t2   = *(const us4*)&sh_t2[e * 104 + mt * 16 + q * 4];
                    f32x2 f01[4]; float fm2[4];
                    #pragma unroll
                    for (int r = 0; r < 4; ++r) {
                        f01[r] = up01(d[r]);
                        fm2[r] = b2f(t2[r]);
                    }
                    #pragma unroll
                    for (int op = 0; op < 4; ++op) {
                        f32x4 z = {0.f, 0.f, 0.f, 0.f};
                        f32x4 acc = MFMA(a[op][0], bh[nt][0], z);
                        acc = MFMA(a[op][1], bh[nt][1], acc);
                        #pragma unroll
                        for (int r = 0; r < 4; ++r) {
                            p01[op][nt] += f01[r] * acc[r];   // v_pk_fma_f32
                            p2v[op][nt] += fm2[r] * acc[r];
                        }
                    }
                }
            }
            // reduce over q (xor 16, 32) and stage into sh_out
            #pragma unroll
            for (int nt = 0; nt < 2; ++nt) {
                #pragma unroll
                for (int op = 0; op < 4; ++op) {
                    float v0 = p01[op][nt][0], v1 = p01[op][nt][1], v2 = p2v[op][nt];
                    v0 += __shfl_xor(v0, 16, 64); v0 += __shfl_xor(v0, 32, 64);
                    v1 += __shfl_xor(v1, 16, 64); v1 += __shfl_xor(v1, 32, 64);
                    v2 += __shfl_xor(v2, 16, 64); v2 += __shfl_xor(v2, 32, 64);
                    float val = (q == 0) ? v0 : ((q == 1) ? v1 : v2);
                    if (q < 3)
                        sh_out[(nt * 16 + n) * 100 + (ob2 + op) * 3 + q] = val;
                }
            }
        }
    }
    __syncthreads();   // barrier 2: sh_out complete

    // coalesced dump: full 384 B per edge, contiguous across threads
    {
        int e = tid >> 3, j0 = (tid & 7) * 12;
        float* op = out + (size_t)(e0 + e) * 96 + j0;
        #pragma unroll
        for (int l = 0; l < 3; ++l) {
            f32x4 v = *(const f32x4*)&sh_out[e * 100 + j0 + l * 4];
            *(f32x4*)(op + l * 4) = v;
        }
    }
}

// ---- launch ----------------------------------------------------------------
extern "C" void kernel_launch(void* const* d_in, const int* in_sizes, int n_in,
                              void* d_out, int out_size, void* d_ws, size_t ws_size,
                              hipStream_t stream) {
    const float* edges = (const float*)d_in[0];
    const float* feats = (const float*)d_in[1];
    const float* basis = (const float*)d_in[2];
    const float* W1  = (const float*)d_in[3];
    const float* b1  = (const float*)d_in[4];
    const float* g1  = (const float*)d_in[5];
    const float* be1 = (const float*)d_in[6];
    const float* W2  = (const float*)d_in[7];
    const float* b2  = (const float*)d_in[8];
    const float* g2  = (const float*)d_in[9];
    const float* be2 = (const float*)d_in[10];
    const float* W3  = (const float*)d_in[11];
    uint16_t* wt  = (uint16_t*)d_ws;          // 405504 B weights + 4 MiB h_g
    uint16_t* h_g = wt + H_OFF;
    float* out = (float*)d_out;

    const int E = in_sizes[0] / 32;           // 32768
    hipLaunchKernelGGL(prep_weights, dim3(216), dim3(256), 0, stream, W1, W2, W3, wt);
    hipLaunchKernelGGL(mlp_kernel, dim3(E / 16), dim3(64), 0, stream,
                       edges, b1, g1, be1, b2, g2, be2, wt, h_g);
    hipLaunchKernelGGL(conv_kernel, dim3(E / 32), dim3(256), 0, stream,
                       feats, basis, wt, h_g, out);
}

// Round 10
// 127.263 us; speedup vs baseline: 1.6854x; 1.1445x over previous
//
#include <hip/hip_runtime.h>
#include <cstdint>
#include <cstddef>

// ---- types ----------------------------------------------------------------
typedef __bf16 bf8 __attribute__((ext_vector_type(8)));
typedef float f32x4 __attribute__((ext_vector_type(4)));
typedef float f32x2 __attribute__((ext_vector_type(2)));
typedef float f32x4u __attribute__((ext_vector_type(4), aligned(4)));
typedef unsigned short us8 __attribute__((ext_vector_type(8)));
typedef unsigned short us4 __attribute__((ext_vector_type(4)));
typedef unsigned int u32x4 __attribute__((ext_vector_type(4)));
typedef unsigned int u32x2 __attribute__((ext_vector_type(2)));

__device__ __forceinline__ uint16_t f2b(float f) {
    uint32_t u = __builtin_bit_cast(uint32_t, f);
    u += 0x7FFFu + ((u >> 16) & 1u);          // RNE
    return (uint16_t)(u >> 16);
}
__device__ __forceinline__ float b2f(uint16_t h) {
    uint32_t u = ((uint32_t)h) << 16;
    return __builtin_bit_cast(float, u);
}
#if __has_builtin(__builtin_amdgcn_cvt_pk_bf16_f32)
__device__ __forceinline__ uint32_t pkbf(float a, float b) {
    auto r = __builtin_amdgcn_cvt_pk_bf16_f32(a, b);
    return __builtin_bit_cast(uint32_t, r);
}
#else
__device__ __forceinline__ uint32_t pkbf(float a, float b) {
    return (uint32_t)f2b(a) | ((uint32_t)f2b(b) << 16);
}
#endif
__device__ __forceinline__ f32x2 up01(uint32_t d) {
    f32x2 r;
    r[0] = __builtin_bit_cast(float, d << 16);
    r[1] = __builtin_bit_cast(float, d & 0xffff0000u);
    return r;
}
__device__ __forceinline__ float gelu_fast(float y) {
    float y3 = y * y * y;
    float z2 = 1.5957691216f * (y + 0.044715f * y3);
    float u = __expf(-z2);
    return y * __builtin_amdgcn_rcpf(1.0f + u);
}

#define MFMA(a, b, c) __builtin_amdgcn_mfma_f32_16x16x32_bf16( \
    __builtin_bit_cast(bf8, (a)), __builtin_bit_cast(bf8, (b)), (c), 0, 0, 0)

// ---- prep: cast+transpose weights into ws ---------------------------------
// ws layout (uint16_t): w1t[64][32] @0, w2t[64][64] @2048, w3t[3072][64] @6144
__global__ void prep_weights(const float* __restrict__ W1,
                             const float* __restrict__ W2,
                             const float* __restrict__ W3,
                             uint16_t* __restrict__ wt) {
    __shared__ float tile[32][33];
    int bx = blockIdx.x;
    if (bx < 192) {
        int kb = (bx & 1) * 32;
        int jb = (bx >> 1) * 32;
        int tx = threadIdx.x & 31, ty = threadIdx.x >> 5;   // 32 x 8
        #pragma unroll
        for (int l = 0; l < 4; ++l)
            tile[ty + 8 * l][tx] = W3[(size_t)(kb + ty + 8 * l) * 3072 + jb + tx];
        __syncthreads();
        #pragma unroll
        for (int l = 0; l < 4; ++l) {
            int j = jb + ty + 8 * l;
            wt[6144 + (size_t)j * 64 + kb + tx] = f2b(tile[tx][ty + 8 * l]);
        }
    } else {
        int t = (bx - 192) * 256 + threadIdx.x;   // 0..6143
        if (t < 2048) {                            // W1: [32][64]
            int i = t >> 6, j = t & 63;
            wt[j * 32 + i] = f2b(W1[t]);
        } else {                                   // W2: [64][64]
            int t2 = t - 2048;
            int k = t2 >> 6, j = t2 & 63;
            wt[2048 + j * 64 + k] = f2b(W2[t2]);
        }
    }
}

// ---- fused main kernel ----------------------------------------------------
// Best-known structure (R5/R6: 256 thr / 4 waves / 64 edges / 512 blocks,
// 48 µs). Delta this round: LEAN phase B (R9-proven mapping): thread =
// (e = tid>>2, iq = tid&3) -> 13 coalesced VMEM loads + ~300 VALU instead of
// 64 wave-loads + ~720 VALU per thread. Everything else identical to R5.
__global__ __launch_bounds__(256, 3) void pairconv_main(
    const float* __restrict__ edges, const float* __restrict__ feats,
    const float* __restrict__ basis,
    const float* __restrict__ b1, const float* __restrict__ g1, const float* __restrict__ be1,
    const float* __restrict__ b2, const float* __restrict__ g2, const float* __restrict__ be2,
    const uint16_t* __restrict__ wt, float* __restrict__ out) {

    __shared__ __align__(16) uint32_t sh_t01[64 * 100];   // 25.0 KiB (m0,m1 packed)
    __shared__ __align__(16) uint16_t sh_t2[64 * 104];    // 13.0 KiB (m2)
    __shared__ __align__(16) uint16_t sh_h[4][16 * 64];   // 8 KiB (h1 then h2)

    const int tid = threadIdx.x;
    const int e0 = blockIdx.x * 64;
    const int lane = tid & 63, w = tid >> 6;
    const int n = lane & 15, q = lane >> 4;

    // early-issue: edges for GEMM1 B-frag
    const int eb = e0 + w * 16;
    f32x4 ex0 = *(const f32x4*)(edges + (size_t)(eb + n) * 32 + q * 8);
    f32x4 ex1 = *(const f32x4*)(edges + (size_t)(eb + n) * 32 + q * 8 + 4);

    // ---------------- Phase B (lean, R9-proven mapping) ---------------------
    {
        const int e = tid >> 2, iq = tid & 3;   // 64 edges x 4 quarters (8 i each)
        f32x4 fv[6];
        const float* fp = feats + (size_t)(e0 + e) * 96 + iq * 24;
        #pragma unroll
        for (int l = 0; l < 6; ++l) fv[l] = *(const f32x4u*)(fp + l * 4);
        float bp[27];
        const float* bpp = basis + (size_t)(e0 + e) * 27;
        #pragma unroll
        for (int v = 0; v < 6; ++v) {
            f32x4u t = *(const f32x4u*)(bpp + v * 4);
            bp[v * 4] = t[0]; bp[v * 4 + 1] = t[1]; bp[v * 4 + 2] = t[2]; bp[v * 4 + 3] = t[3];
        }
        bp[24] = bpp[24]; bp[25] = bpp[25]; bp[26] = bpp[26];

        uint32_t t01b[24]; uint16_t t2b[24];
        const float* fvs = (const float*)fv;   // 24 floats = 8 i x 3
        #pragma unroll
        for (int ii = 0; ii < 8; ++ii) {
            float a0 = fvs[ii * 3], a1 = fvs[ii * 3 + 1], a2 = fvs[ii * 3 + 2];
            #pragma unroll
            for (int f = 0; f < 3; ++f) {
                float v0 = a0 * bp[f * 3 + 0] + a1 * bp[9 + f * 3 + 0] + a2 * bp[18 + f * 3 + 0];
                float v1 = a0 * bp[f * 3 + 1] + a1 * bp[9 + f * 3 + 1] + a2 * bp[18 + f * 3 + 1];
                float v2 = a0 * bp[f * 3 + 2] + a1 * bp[9 + f * 3 + 2] + a2 * bp[18 + f * 3 + 2];
                t01b[ii * 3 + f] = pkbf(v0, v1);
                t2b[ii * 3 + f]  = (uint16_t)pkbf(v2, v2);
            }
        }
        const int c0 = iq * 24;
        #pragma unroll
        for (int l = 0; l < 6; ++l)
            *(u32x4*)&sh_t01[e * 100 + c0 + l * 4] = *(u32x4*)&t01b[l * 4];
        #pragma unroll
        for (int l = 0; l < 3; ++l)
            *(us8*)&sh_t2[e * 104 + c0 + l * 8] = *(us8*)&t2b[l * 8];
    }

    // ---------------- Phase C: radial MLP (all 4 waves, 16 edges each) ------
    {
        us8 bx;
        {
            u32x4 bxp;
            bxp[0] = pkbf(ex0[0], ex0[1]); bxp[1] = pkbf(ex0[2], ex0[3]);
            bxp[2] = pkbf(ex1[0], ex1[1]); bxp[3] = pkbf(ex1[2], ex1[3]);
            bx = __builtin_bit_cast(us8, bxp);
        }
        f32x4 acc[4];
        #pragma unroll
        for (int mt = 0; mt < 4; ++mt) {
            us8 a = *(const us8*)(wt + (mt * 16 + n) * 32 + q * 8);
            f32x4 z = {0.f, 0.f, 0.f, 0.f};
            acc[mt] = MFMA(a, bx, z);
        }
        float v[4][4];
        float s1 = 0.f, s2 = 0.f;
        #pragma unroll
        for (int mt = 0; mt < 4; ++mt) {
            f32x4 bb = *(const f32x4*)&b1[mt * 16 + q * 4];
            #pragma unroll
            for (int r = 0; r < 4; ++r) {
                float x = acc[mt][r] + bb[r];
                v[mt][r] = x; s1 += x; s2 += x * x;
            }
        }
        s1 += __shfl_xor(s1, 16, 64); s1 += __shfl_xor(s1, 32, 64);
        s2 += __shfl_xor(s2, 16, 64); s2 += __shfl_xor(s2, 32, 64);
        float mean = s1 * (1.f / 64.f);
        float var  = s2 * (1.f / 64.f) - mean * mean;
        float rs = __builtin_amdgcn_rsqf(var + 1e-5f);
        #pragma unroll
        for (int mt = 0; mt < 4; ++mt) {
            f32x4 gg = *(const f32x4*)&g1[mt * 16 + q * 4];
            f32x4 be = *(const f32x4*)&be1[mt * 16 + q * 4];
            float y0 = gelu_fast((v[mt][0] - mean) * rs * gg[0] + be[0]);
            float y1 = gelu_fast((v[mt][1] - mean) * rs * gg[1] + be[1]);
            float y2 = gelu_fast((v[mt][2] - mean) * rs * gg[2] + be[2]);
            float y3 = gelu_fast((v[mt][3] - mean) * rs * gg[3] + be[3]);
            u32x2 pk; pk[0] = pkbf(y0, y1); pk[1] = pkbf(y2, y3);
            int kq = mt * 2 + (q >> 1);
            *(u32x2*)&sh_h[w][n * 64 + ((kq ^ (n & 7)) << 3) + (q & 1) * 4] = pk;
        }
    }
    // no barrier: sh_h[w] is wave-private until the block barrier below
    {
        us8 bh0 = *(const us8*)&sh_h[w][n * 64 + ((q ^ (n & 7)) << 3)];
        us8 bh1 = *(const us8*)&sh_h[w][n * 64 + (((4 + q) ^ (n & 7)) << 3)];
        f32x4 acc[4];
        #pragma unroll
        for (int mt = 0; mt < 4; ++mt) {
            us8 a0 = *(const us8*)(wt + 2048 + (mt * 16 + n) * 64 + q * 8);
            us8 a1 = *(const us8*)(wt + 2048 + (mt * 16 + n) * 64 + 32 + q * 8);
            f32x4 z = {0.f, 0.f, 0.f, 0.f};
            acc[mt] = MFMA(a0, bh0, z);
            acc[mt] = MFMA(a1, bh1, acc[mt]);
        }
        float v[4][4]; float s1 = 0.f, s2 = 0.f;
        #pragma unroll
        for (int mt = 0; mt < 4; ++mt) {
            f32x4 bb = *(const f32x4*)&b2[mt * 16 + q * 4];
            #pragma unroll
            for (int r = 0; r < 4; ++r) {
                float x = acc[mt][r] + bb[r];
                v[mt][r] = x; s1 += x; s2 += x * x;
            }
        }
        s1 += __shfl_xor(s1, 16, 64); s1 += __shfl_xor(s1, 32, 64);
        s2 += __shfl_xor(s2, 16, 64); s2 += __shfl_xor(s2, 32, 64);
        float mean = s1 * (1.f / 64.f);
        float var  = s2 * (1.f / 64.f) - mean * mean;
        float rs = __builtin_amdgcn_rsqf(var + 1e-5f);
        #pragma unroll
        for (int mt = 0; mt < 4; ++mt) {
            f32x4 gg = *(const f32x4*)&g2[mt * 16 + q * 4];
            f32x4 be = *(const f32x4*)&be2[mt * 16 + q * 4];
            float y0 = gelu_fast((v[mt][0] - mean) * rs * gg[0] + be[0]);
            float y1 = gelu_fast((v[mt][1] - mean) * rs * gg[1] + be[1]);
            float y2 = gelu_fast((v[mt][2] - mean) * rs * gg[2] + be[2]);
            float y3 = gelu_fast((v[mt][3] - mean) * rs * gg[3] + be[3]);
            u32x2 pk; pk[0] = pkbf(y0, y1); pk[1] = pkbf(y2, y3);
            int kq = mt * 2 + (q >> 1);
            // overwrite h1 slot with h2 (same-wave DS ordering; proven)
            *(u32x2*)&sh_h[w][n * 64 + ((kq ^ (n & 7)) << 3) + (q & 1) * 4] = pk;
        }
    }
    __syncthreads();   // the ONLY barrier

    // ---------------- Phase D: rw = h @ W3T fused with c-contraction --------
    // wave w handles o in [w*8, w*8+8) over all 64 edges (nt = 0..3)
    {
        const uint16_t* w3t = wt + 6144;
        us8 bh[4][2];
        #pragma unroll
        for (int nt = 0; nt < 4; ++nt) {
            bh[nt][0] = *(const us8*)&sh_h[nt][n * 64 + ((q ^ (n & 7)) << 3)];
            bh[nt][1] = *(const us8*)&sh_h[nt][n * 64 + (((4 + q) ^ (n & 7)) << 3)];
        }
        const int ob = w * 8;
        #pragma unroll 1
        for (int oc = 0; oc < 2; ++oc) {
            f32x2 p01[4][4];   // [op][nt] (m0,m1)
            float p2v[4][4];
            #pragma unroll
            for (int op = 0; op < 4; ++op)
                #pragma unroll
                for (int nt = 0; nt < 4; ++nt) {
                    p01[op][nt] = (f32x2){0.f, 0.f}; p2v[op][nt] = 0.f;
                }

            #pragma unroll 1
            for (int mt = 0; mt < 6; ++mt) {
                us8 a[4][2];
                const uint16_t* apb = w3t +
                    (size_t)((ob + oc * 4) * 96 + mt * 16 + n) * 64 + q * 8;
                #pragma unroll
                for (int op = 0; op < 4; ++op) {
                    a[op][0] = *(const us8*)(apb + (size_t)op * 6144);
                    a[op][1] = *(const us8*)(apb + (size_t)op * 6144 + 32);
                }
                #pragma unroll
                for (int nt = 0; nt < 4; ++nt) {
                    int e = nt * 16 + n;
                    u32x4 d  = *(const u32x4*)&sh_t01[e * 100 + mt * 16 + q * 4];
                    us4 t2   = *(const us4*)&sh_t2[e * 104 + mt * 16 + q * 4];
                    f32x2 f01[4]; float fm2[4];
                    #pragma unroll
                    for (int r = 0; r < 4; ++r) {
                        f01[r] = up01(d[r]);
                        fm2[r] = b2f(t2[r]);
                    }
                    #pragma unroll
                    for (int op = 0; op < 4; ++op) {
                        f32x4 z = {0.f, 0.f, 0.f, 0.f};
                        f32x4 acc = MFMA(a[op][0], bh[nt][0], z);
                        acc = MFMA(a[op][1], bh[nt][1], acc);
                        #pragma unroll
                        for (int r = 0; r < 4; ++r) {
                            p01[op][nt] += f01[r] * acc[r];   // v_pk_fma_f32
                            p2v[op][nt] += fm2[r] * acc[r];
                        }
                    }
                }
            }
            // reduce over q (xor 16, 32) and store
            #pragma unroll
            for (int nt = 0; nt < 4; ++nt) {
                #pragma unroll
                for (int op = 0; op < 4; ++op) {
                    int o = ob + oc * 4 + op;
                    float v0 = p01[op][nt][0], v1 = p01[op][nt][1], v2 = p2v[op][nt];
                    v0 += __shfl_xor(v0, 16, 64); v0 += __shfl_xor(v0, 32, 64);
                    v1 += __shfl_xor(v1, 16, 64); v1 += __shfl_xor(v1, 32, 64);
                    v2 += __shfl_xor(v2, 16, 64); v2 += __shfl_xor(v2, 32, 64);
                    float val = (q == 0) ? v0 : ((q == 1) ? v1 : v2);
                    if (q < 3)
                        out[(size_t)(e0 + nt * 16 + n) * 96 + o * 3 + q] = val;
                }
            }
        }
    }
}

// ---- launch ----------------------------------------------------------------
extern "C" void kernel_launch(void* const* d_in, const int* in_sizes, int n_in,
                              void* d_out, int out_size, void* d_ws, size_t ws_size,
                              hipStream_t stream) {
    const float* edges = (const float*)d_in[0];
    const float* feats = (const float*)d_in[1];
    const float* basis = (const float*)d_in[2];
    const float* W1  = (const float*)d_in[3];
    const float* b1  = (const float*)d_in[4];
    const float* g1  = (const float*)d_in[5];
    const float* be1 = (const float*)d_in[6];
    const float* W2  = (const float*)d_in[7];
    const float* b2  = (const float*)d_in[8];
    const float* g2  = (const float*)d_in[9];
    const float* be2 = (const float*)d_in[10];
    const float* W3  = (const float*)d_in[11];
    uint16_t* wt = (uint16_t*)d_ws;           // 202752 uint16 = 405504 B
    float* out = (float*)d_out;

    const int E = in_sizes[0] / 32;           // 32768
    hipLaunchKernelGGL(prep_weights, dim3(216), dim3(256), 0, stream, W1, W2, W3, wt);
    hipLaunchKernelGGL(pairconv_main, dim3(E / 64), dim3(256), 0, stream,
                       edges, feats, basis, b1, g1, be1, b2, g2, be2, wt, out);
}